// Round 3
// baseline (159.283 us; speedup 1.0000x reference)
//
#include <hip/hip_runtime.h>
#include <hip/hip_bf16.h>

#define NQ 12
#define DIM 4096          // 2^12
#define NPAIR (DIM / 2)
#define NTHREADS 256

// One block per batch element. State (4096 complex) lives in LDS as SoA
// float arrays. Gates applied sequentially; each gate partitions the state
// into disjoint (i0,i1) pairs, so only inter-gate __syncthreads() needed.
// Wire q (PennyLane big-endian reshape) == bit (NQ-1-q) of the flat index.
// dtypes: inputs fp32 (round-1 NaN proves storage is fp32), output fp32
// (reference output dtype per contract; round-2 bf16 writes scrambled the
// fp32 buffer -> absmax 0.48).
__global__ __launch_bounds__(NTHREADS) void qsim_kernel(
    const float* __restrict__ x,   // (B, 12) angles, fp32
    const float* __restrict__ w,   // (2, 12, 3) Rot params, fp32
    float* __restrict__ out)       // (B, 12) <Z_q>, fp32
{
    __shared__ float sRe[DIM];
    __shared__ float sIm[DIM];
    __shared__ float rotm[2][NQ][8];   // per (layer,wire): u00,u01,u10,u11 (re,im)
    __shared__ float ryc[NQ], rys[NQ];
    __shared__ float red[4][NQ];

    const int tid = threadIdx.x;
    const int b = blockIdx.x;

    // --- init |0...0> ---
    for (int i = tid; i < DIM; i += NTHREADS) { sRe[i] = 0.f; sIm[i] = 0.f; }
    if (tid == 0) sRe[0] = 1.f;

    // --- precompute RY cos/sin (same for both layers: data re-uploading) ---
    if (tid < NQ) {
        float th = 0.5f * x[b * NQ + tid];
        ryc[tid] = cosf(th);
        rys[tid] = sinf(th);
    }
    // --- precompute Rot matrices (batch-independent) ---
    if (tid >= 64 && tid < 64 + 2 * NQ) {    // different wave than RY calc
        int t = tid - 64;
        int l = t / NQ, q = t % NQ;
        const float* wp = w + (l * NQ + q) * 3;
        float phi = wp[0];
        float th  = wp[1];
        float om  = wp[2];
        float c = cosf(0.5f * th), s = sinf(0.5f * th);
        float al = 0.5f * (phi + om), be = 0.5f * (phi - om);
        float ca = cosf(al), sa = sinf(al);
        float cb = cosf(be), sb = sinf(be);
        float* m = rotm[l][q];
        m[0] = ca * c;  m[1] = -sa * c;   // u00 = e^{-i a} c
        m[2] = -cb * s; m[3] = -sb * s;   // u01 = -e^{+i b} s
        m[4] = cb * s;  m[5] = -sb * s;   // u10 = e^{-i b} s
        m[6] = ca * c;  m[7] = sa * c;    // u11 = e^{+i a} c
    }
    __syncthreads();

    for (int l = 0; l < 2; ++l) {
        // ---- AngleEmbedding: RY(x[b,q]) on each wire ----
        for (int q = 0; q < NQ; ++q) {
            const int bit = NQ - 1 - q;
            const int str = 1 << bit;
            const float c = ryc[q], s = rys[q];
            for (int p = tid; p < NPAIR; p += NTHREADS) {
                int i0 = ((p >> bit) << (bit + 1)) | (p & (str - 1));
                int i1 = i0 | str;
                float ar = sRe[i0], ai = sIm[i0];
                float br = sRe[i1], bi = sIm[i1];
                sRe[i0] = c * ar - s * br;  sIm[i0] = c * ai - s * bi;
                sRe[i1] = s * ar + c * br;  sIm[i1] = s * ai + c * bi;
            }
            __syncthreads();
        }
        // ---- SEL Rot per wire ----
        for (int q = 0; q < NQ; ++q) {
            const int bit = NQ - 1 - q;
            const int str = 1 << bit;
            const float* m = rotm[l][q];
            const float u00r = m[0], u00i = m[1], u01r = m[2], u01i = m[3];
            const float u10r = m[4], u10i = m[5], u11r = m[6], u11i = m[7];
            for (int p = tid; p < NPAIR; p += NTHREADS) {
                int i0 = ((p >> bit) << (bit + 1)) | (p & (str - 1));
                int i1 = i0 | str;
                float ar = sRe[i0], ai = sIm[i0];
                float br = sRe[i1], bi = sIm[i1];
                sRe[i0] = u00r * ar - u00i * ai + u01r * br - u01i * bi;
                sIm[i0] = u00r * ai + u00i * ar + u01r * bi + u01i * br;
                sRe[i1] = u10r * ar - u10i * ai + u11r * br - u11i * bi;
                sIm[i1] = u10r * ai + u10i * ar + u11r * bi + u11i * br;
            }
            __syncthreads();
        }
        // ---- CNOT ring, range 1 ----
        for (int q = 0; q < NQ; ++q) {
            const int cbit = NQ - 1 - q;
            const int tbit = NQ - 1 - ((q + 1) % NQ);
            const int b1 = (cbit < tbit) ? cbit : tbit;
            const int b2 = (cbit < tbit) ? tbit : cbit;
            for (int p = tid; p < DIM / 4; p += NTHREADS) {
                int i = ((p >> b1) << (b1 + 1)) | (p & ((1 << b1) - 1));
                i = ((i >> b2) << (b2 + 1)) | (i & ((1 << b2) - 1));
                int i0 = i | (1 << cbit);        // control=1, target=0
                int i1 = i0 | (1 << tbit);       // control=1, target=1
                float tr = sRe[i0], ti = sIm[i0];
                sRe[i0] = sRe[i1]; sIm[i0] = sIm[i1];
                sRe[i1] = tr;      sIm[i1] = ti;
            }
            __syncthreads();
        }
    }

    // ---- <Z_q> = sum_{bit(11-q)=0} |a|^2 - sum_{bit=1} |a|^2 ----
    // Thread holds 16 contiguous amplitudes: i = tid*16 + k. Bits 4..11 of i
    // come from tid (sign constant per thread); bits 0..3 from k.
    float tot = 0.f, t0 = 0.f, t1 = 0.f, t2 = 0.f, t3 = 0.f;
    const int base = tid * 16;
    for (int k = 0; k < 16; ++k) {
        int i = base + k;
        float p = sRe[i] * sRe[i] + sIm[i] * sIm[i];
        tot += p;
        t0 += ((k >> 0) & 1) ? -p : p;
        t1 += ((k >> 1) & 1) ? -p : p;
        t2 += ((k >> 2) & 1) ? -p : p;
        t3 += ((k >> 3) & 1) ? -p : p;
    }
    float v[NQ];
    for (int q = 0; q < 8; ++q) {              // bit = 11-q in [4,11]
        int bit = NQ - 1 - q;
        int tb = (tid >> (bit - 4)) & 1;
        v[q] = tb ? -tot : tot;
    }
    v[8] = t3; v[9] = t2; v[10] = t1; v[11] = t0;

    const int lane = tid & 63, wv = tid >> 6;
    for (int q = 0; q < NQ; ++q) {
        float r = v[q];
        for (int off = 32; off > 0; off >>= 1) r += __shfl_down(r, off, 64);
        if (lane == 0) red[wv][q] = r;
    }
    __syncthreads();
    if (tid < NQ) {
        float r = red[0][tid] + red[1][tid] + red[2][tid] + red[3][tid];
        out[b * NQ + tid] = r;
    }
}

extern "C" void kernel_launch(void* const* d_in, const int* in_sizes, int n_in,
                              void* d_out, int out_size, void* d_ws, size_t ws_size,
                              hipStream_t stream) {
    // Select by size (x has B*12 = 12288 elems, weights has 2*12*3 = 72):
    // insurance against input-ordering surprises.
    int xi = 0, wi = 1;
    if (n_in >= 2 && in_sizes[1] > in_sizes[0]) { xi = 1; wi = 0; }
    const float* x = (const float*)d_in[xi];
    const float* w = (const float*)d_in[wi];
    float* out = (float*)d_out;
    const int B = in_sizes[xi] / NQ;   // 1024
    qsim_kernel<<<B, NTHREADS, 0, stream>>>(x, w, out);
}

// Round 4
// 85.105 us; speedup vs baseline: 1.8716x; 1.8716x over previous
//
#include <hip/hip_runtime.h>

#define NQ 12
#define DIM 4096
#define NT 256

// ---------- compile-time index machinery (all GF(2)-linear) ----------
// Bank swizzle: slot(i) = i ^ (((i>>5)^(i>>9))&31). Linear bijection chosen so
// every pass pattern below hits 32 banks with 2 lanes/bank (free, m136).
__host__ __device__ constexpr int SW(int i) { return i ^ (((i >> 5) ^ (i >> 9)) & 31); }
__host__ __device__ constexpr int par(int v) { v ^= v >> 8; v ^= v >> 4; v ^= v >> 2; v ^= v >> 1; return v & 1; }
// CNOT ring permutation (wire q = bit 11-q; ring CNOT(q,q+1 mod 12), applied
// sequentially). Linear: y_k = parity(bits >= k) for k<=10; y_11 = parity(bits<=10).
// Verified: ringP(0x800)=0x7FF, ringP(1)=0x801.
__host__ __device__ constexpr int ringP(int i) {
    int r = 0;
    for (int k = 0; k <= 10; ++k) r |= par((i >> k) & 0xFFF) << k;
    r |= par(i & 0x7FF) << 11;
    return r;
}

// ---------- one gate pass: 4 fused 1q gates applied in registers ----------
// P=0: gate bits i[11:8] (wires 0-3),  thread owns i[7:0]=t,  i=(k<<8)|t
// P=1: gate bits i[7:4]  (wires 4-7),  thread owns i[3:0]=t[3:0], i[11:8]=t[7:4]
// P=2: gate bits i[3:0]  (wires 8-11), thread owns i[11:4]=t, i=(t<<4)|k
// SCAT: write through the CNOT-ring permutation (slot(ringP(i))) with a
// barrier between the read/compute phase and the scattered writes.
template <int P, bool SCAT>
__device__ __forceinline__ void gate_pass(float* sRe, float* sIm,
                                          const float (*fml)[8],
                                          int base, int scbase) {
    float ar[16], ai[16];
#pragma unroll
    for (int k = 0; k < 16; ++k) {
        int a = base ^ (P == 0 ? SW(k << 8) : P == 1 ? SW(k << 4) : k);
        ar[k] = sRe[a]; ai[k] = sIm[a];
    }
    const int w0 = P * 4;
#pragma unroll
    for (int j = 3; j >= 0; --j) {
        // k-bit j corresponds to wire w0 + (3-j)
        const float* m = fml[w0 + (3 - j)];
        float4 mlo = *(const float4*)m;        // U00, U01 (re,im,re,im)
        float4 mhi = *(const float4*)(m + 4);  // U10, U11
#pragma unroll
        for (int k = 0; k < 16; ++k) {
            if (k & (1 << j)) continue;
            int k1 = k | (1 << j);
            float a0r = ar[k], a0i = ai[k], a1r = ar[k1], a1i = ai[k1];
            ar[k]  = mlo.x * a0r - mlo.y * a0i + mlo.z * a1r - mlo.w * a1i;
            ai[k]  = mlo.x * a0i + mlo.y * a0r + mlo.z * a1i + mlo.w * a1r;
            ar[k1] = mhi.x * a0r - mhi.y * a0i + mhi.z * a1r - mhi.w * a1i;
            ai[k1] = mhi.x * a0i + mhi.y * a0r + mhi.z * a1i + mhi.w * a1r;
        }
    }
    if (SCAT) __syncthreads();   // all reads done before any scattered write
#pragma unroll
    for (int k = 0; k < 16; ++k) {
        int a = SCAT ? (scbase ^ SW(ringP(k)))
                     : (base ^ (P == 0 ? SW(k << 8) : P == 1 ? SW(k << 4) : k));
        sRe[a] = ar[k]; sIm[a] = ai[k];
    }
    __syncthreads();
}

__global__ __launch_bounds__(NT, 4) void qsim_kernel(
    const float* __restrict__ x,   // (B, 12) fp32
    const float* __restrict__ w,   // (2, 12, 3) fp32
    float* __restrict__ out)       // (B, 12) fp32
{
    __shared__ float sRe[DIM];
    __shared__ float sIm[DIM];
    __shared__ __align__(16) float fm[2][NQ][8];  // fused U = Rot*RY per (layer,wire)
    __shared__ float red[4][NQ];

    const int t = threadIdx.x;
    const int b = blockIdx.x;

    // init |0..0> (slot SW(0)=0)
    for (int a = t; a < DIM; a += NT) { sRe[a] = 0.f; sIm[a] = 0.f; }
    if (t == 0) sRe[0] = 1.f;

    // fused gate matrices: U = Rot(phi,theta,omega) * RY(x_q)
    if (t < 2 * NQ) {
        int l = t / NQ, q = t % NQ;
        float hy = 0.5f * x[b * NQ + q];
        float cy = cosf(hy), sy = sinf(hy);
        const float* wp = w + (l * NQ + q) * 3;
        float phi = wp[0], the = wp[1], om = wp[2];
        float c = cosf(0.5f * the), s = sinf(0.5f * the);
        float al = 0.5f * (phi + om), be = 0.5f * (phi - om);
        float ca = cosf(al), sa = sinf(al), cb = cosf(be), sb = sinf(be);
        float r00r =  ca * c, r00i = -sa * c;   // e^{-ia} c
        float r01r = -cb * s, r01i = -sb * s;   // -e^{+ib} s
        float r10r =  cb * s, r10i = -sb * s;   // e^{-ib} s
        float r11r =  ca * c, r11i =  sa * c;   // e^{+ia} c
        float* m = fm[l][q];
        m[0] =  r00r * cy + r01r * sy;  m[1] =  r00i * cy + r01i * sy;  // U00
        m[2] = -r00r * sy + r01r * cy;  m[3] = -r00i * sy + r01i * cy;  // U01
        m[4] =  r10r * cy + r11r * sy;  m[5] =  r10i * cy + r11i * sy;  // U10
        m[6] = -r10r * sy + r11r * cy;  m[7] = -r10i * sy + r11i * cy;  // U11
    }
    __syncthreads();

    // per-thread pass base addresses (slot of the thread-fixed bits)
    const int baseA = t ^ ((t >> 5) & 31);                       // SW(t)
    const int tpB   = ((t & 0xF0) << 4) | (t & 15);
    const int baseB = SW(tpB);
    const int baseC = SW(t << 4);
    const int scb   = SW(ringP(t << 4));                         // scatter base

    for (int l = 0; l < 2; ++l) {
        gate_pass<0, false>(sRe, sIm, fm[l], baseA, 0);
        gate_pass<1, false>(sRe, sIm, fm[l], baseB, 0);
        gate_pass<2, true >(sRe, sIm, fm[l], baseC, scb);  // + CNOT ring fold
    }

    // epilogue: <Z_q>. Read in pass-A pattern: i = (k<<8)|t.
    // wires 0-3 <- k bits 3..0 (in-thread); wires 4-11 <- t bits 7..0 (fixed).
    float tot = 0.f, z0 = 0.f, z1 = 0.f, z2 = 0.f, z3 = 0.f;
#pragma unroll
    for (int k = 0; k < 16; ++k) {
        int a = baseA ^ SW(k << 8);
        float re = sRe[a], im = sIm[a];
        float p = re * re + im * im;
        tot += p;
        z0 += (k & 8) ? -p : p;
        z1 += (k & 4) ? -p : p;
        z2 += (k & 2) ? -p : p;
        z3 += (k & 1) ? -p : p;
    }
    float v[NQ];
    v[0] = z0; v[1] = z1; v[2] = z2; v[3] = z3;
#pragma unroll
    for (int q = 4; q < NQ; ++q) v[q] = ((t >> (11 - q)) & 1) ? -tot : tot;

    const int lane = t & 63, wv = t >> 6;
#pragma unroll
    for (int q = 0; q < NQ; ++q) {
        float r = v[q];
        for (int off = 32; off > 0; off >>= 1) r += __shfl_down(r, off, 64);
        if (lane == 0) red[wv][q] = r;
    }
    __syncthreads();
    if (t < NQ) {
        out[b * NQ + t] = red[0][t] + red[1][t] + red[2][t] + red[3][t];
    }
}

extern "C" void kernel_launch(void* const* d_in, const int* in_sizes, int n_in,
                              void* d_out, int out_size, void* d_ws, size_t ws_size,
                              hipStream_t stream) {
    int xi = 0, wi = 1;
    if (n_in >= 2 && in_sizes[1] > in_sizes[0]) { xi = 1; wi = 0; }
    const float* x = (const float*)d_in[xi];
    const float* w = (const float*)d_in[wi];
    float* out = (float*)d_out;
    const int B = in_sizes[xi] / NQ;   // 1024
    qsim_kernel<<<B, NT, 0, stream>>>(x, w, out);
}